// Round 3
// baseline (150.588 us; speedup 1.0000x reference)
//
#include <hip/hip_runtime.h>

// Batched tiny GRU: B=512, T=4096, C=hidden=4.
// Chunked scan with warmup: CHUNK=32, WARM=64 -> 1024 waves = 1 wave/SIMD.
// R3 change: __launch_bounds__(64, 1). R2's prefetch was defeated by a
// 64-VGPR allocation (compiler sank loads to uses, serialized gate ILP).
// At 1 wave/SIMD, occupancy is fixed by grid size -> spend VGPRs on real
// double-buffered loads + balanced FMA trees instead.

#define TB 512
#define TC 4
#define TT 4096
#define BC (TB * TC)
#define CHUNK 32
#define WARM 64
#define NCH (TT / CHUNK)

__device__ __forceinline__ float fexp2(float x) { return __builtin_amdgcn_exp2f(x); }
__device__ __forceinline__ float frcp(float x)  { return __builtin_amdgcn_rcpf(x); }
__device__ __forceinline__ float fsigmoid(float x) {
    return frcp(1.0f + fexp2(x * -1.4426950408889634f));
}
__device__ __forceinline__ float ftanh_fast(float x) {
    return 1.0f - 2.0f * frcp(1.0f + fexp2(x * 2.8853900817779268f));
}

// [2048][4096] -> [4096][2048] f32 transpose. 64x64 tiles, float4 global on
// both sides, stride-65 LDS (2-way bank aliasing only = free).
__global__ __launch_bounds__(256) void transpose_k(const float* __restrict__ in,
                                                   float* __restrict__ out) {
    __shared__ float tile[64 * 65];
    const int tid = threadIdx.x;
    const int t0 = blockIdx.x * 64;
    const int r0 = blockIdx.y * 64;  // bc
    const float4* in4 = (const float4*)in;
    float4* out4 = (float4*)out;

    const int f4c = tid & 15;
    const int row = tid >> 4;
#pragma unroll
    for (int rr = 0; rr < 64; rr += 16) {
        float4 v = in4[(size_t)(r0 + row + rr) * (TT / 4) + (t0 >> 2) + f4c];
        const int tl = f4c * 4;
        const int bcl = row + rr;
        tile[(tl + 0) * 65 + bcl] = v.x;
        tile[(tl + 1) * 65 + bcl] = v.y;
        tile[(tl + 2) * 65 + bcl] = v.z;
        tile[(tl + 3) * 65 + bcl] = v.w;
    }
    __syncthreads();
    const int c2 = tid & 15;
    const int trw = tid >> 4;
#pragma unroll
    for (int rr = 0; rr < 64; rr += 16) {
        const int t = trw + rr;
        float4 v;
        v.x = tile[t * 65 + c2 * 4 + 0];
        v.y = tile[t * 65 + c2 * 4 + 1];
        v.z = tile[t * 65 + c2 * 4 + 2];
        v.w = tile[t * 65 + c2 * 4 + 3];
        out4[(size_t)(t0 + t) * (BC / 4) + (r0 >> 2) + c2] = v;
    }
}

__global__ __launch_bounds__(64, 1) void gru_scan(
    const float* __restrict__ xt, const float* __restrict__ wih,
    const float* __restrict__ whh, const float* __restrict__ bih,
    const float* __restrict__ bhh, float* __restrict__ out) {
    const int b = blockIdx.x * 64 + threadIdx.x;
    const int ch = blockIdx.y;
    const int t0 = ch * CHUNK;
    const int tw = (t0 >= WARM) ? (t0 - WARM) : 0;

    // Wave-uniform weights -> SGPRs.
    float Wi[12][4], Wh[12][4], bg[12], bhn[4];
#pragma unroll
    for (int g = 0; g < 12; ++g) {
#pragma unroll
        for (int c = 0; c < 4; ++c) {
            Wi[g][c] = wih[g * 4 + c];
            Wh[g][c] = whh[g * 4 + c];
        }
        bg[g] = bih[g] + ((g < 8) ? bhh[g] : 0.0f);
    }
#pragma unroll
    for (int j = 0; j < 4; ++j) bhn[j] = bhh[8 + j];

    float h0 = 0.f, h1 = 0.f, h2 = 0.f, h3 = 0.f;
    const float4* xt4 = (const float4*)xt;

    auto ld = [&](int t) {
        int tc = (t < TT - 1) ? t : (TT - 1);  // uniform clamp for prefetch tail
        return xt4[(size_t)tc * TB + b];
    };

    // Balanced-tree GRU step: x-part and h-part each depth-3, 12 independent
    // gate chains for the scheduler to interleave.
    auto step = [&](float4 xv) {
        float xs[12], a[12];
#pragma unroll
        for (int g = 0; g < 12; ++g) {
            float e1 = fmaf(Wi[g][1], xv.y, Wi[g][0] * xv.x);
            float e2 = fmaf(Wi[g][3], xv.w, Wi[g][2] * xv.z);
            xs[g] = (e1 + e2) + bg[g];
        }
#pragma unroll
        for (int g = 0; g < 12; ++g) {
            float o1 = fmaf(Wh[g][1], h1, Wh[g][0] * h0);
            float o2 = fmaf(Wh[g][3], h3, Wh[g][2] * h2);
            a[g] = (g < 8) ? (xs[g] + (o1 + o2)) : (o1 + o2) + bhn[g - 8];
        }
        float r0 = fsigmoid(a[0]), r1 = fsigmoid(a[1]);
        float r2 = fsigmoid(a[2]), r3 = fsigmoid(a[3]);
        float z0 = fsigmoid(a[4]), z1 = fsigmoid(a[5]);
        float z2 = fsigmoid(a[6]), z3 = fsigmoid(a[7]);
        float n0 = ftanh_fast(fmaf(r0, a[8], xs[8]));
        float n1 = ftanh_fast(fmaf(r1, a[9], xs[9]));
        float n2 = ftanh_fast(fmaf(r2, a[10], xs[10]));
        float n3 = ftanh_fast(fmaf(r3, a[11], xs[11]));
        h0 = fmaf(z0, h0 - n0, n0);
        h1 = fmaf(z1, h1 - n1, n1);
        h2 = fmaf(z2, h2 - n2, n2);
        h3 = fmaf(z3, h3 - n3, n3);
    };

    // 8-step groups, double-buffered prefetch. ng ∈ {4,8,12}, even.
    const int ng = (t0 - tw + CHUNK) / 8;
    const int nwarm = ng - 4;

    float4 xa[8], xb[8];
#pragma unroll
    for (int s = 0; s < 8; ++s) xa[s] = ld(tw + s);

    float ob[4][16];

    for (int g = 0; g < ng; g += 2) {
        const int tg = tw + g * 8;
        // phase A: prefetch group g+1, compute group g (xa)
#pragma unroll
        for (int s = 0; s < 8; ++s) xb[s] = ld(tg + 8 + s);
        if (g >= nwarm) {
#pragma unroll
            for (int s = 0; s < 8; ++s) {
                step(xa[s]);
                ob[0][s] = h0; ob[1][s] = h1; ob[2][s] = h2; ob[3][s] = h3;
            }
        } else {
#pragma unroll
            for (int s = 0; s < 8; ++s) step(xa[s]);
        }
        // phase B: prefetch group g+2, compute group g+1 (xb)
#pragma unroll
        for (int s = 0; s < 8; ++s) xa[s] = ld(tg + 16 + s);
        if (g + 1 >= nwarm) {
#pragma unroll
            for (int s = 0; s < 8; ++s) {
                step(xb[s]);
                ob[0][8 + s] = h0; ob[1][8 + s] = h1;
                ob[2][8 + s] = h2; ob[3][8 + s] = h3;
            }
            // flush 16 steps = 64B contiguous per (b,c)
            const int e = (g + 1) - nwarm;  // 1 or 3
            const int tf = t0 + (e - 1) * 8;
#pragma unroll
            for (int c = 0; c < 4; ++c) {
                float4* op = (float4*)&out[((size_t)(b * 4 + c)) * TT + tf];
#pragma unroll
                for (int q = 0; q < 4; ++q)
                    op[q] = make_float4(ob[c][q * 4 + 0], ob[c][q * 4 + 1],
                                        ob[c][q * 4 + 2], ob[c][q * 4 + 3]);
            }
        } else {
#pragma unroll
            for (int s = 0; s < 8; ++s) step(xb[s]);
        }
    }
}

extern "C" void kernel_launch(void* const* d_in, const int* in_sizes, int n_in,
                              void* d_out, int out_size, void* d_ws, size_t ws_size,
                              hipStream_t stream) {
    const float* x   = (const float*)d_in[0];
    const float* wih = (const float*)d_in[1];
    const float* whh = (const float*)d_in[2];
    const float* bih = (const float*)d_in[3];
    const float* bhh = (const float*)d_in[4];
    float* out = (float*)d_out;
    float* xtr = (float*)d_ws;  // 32 MiB scratch

    transpose_k<<<dim3(TT / 64, BC / 64), 256, 0, stream>>>(x, xtr);
    gru_scan<<<dim3(TB / 64, NCH), 64, 0, stream>>>(xtr, wih, whh, bih, bhh, out);
}

// Round 4
// 140.615 us; speedup vs baseline: 1.0709x; 1.0709x over previous
//
#include <hip/hip_runtime.h>

// Batched tiny GRU: B=512, T=4096, C=hidden=4.
// R4: CHUNK=16/WARM=48 -> 2048 waves = 2 waves/SIMD (TLP hides stalls that
// source pipelining couldn't at 1 wave/SIMD). Transpose pass removed: scan
// reads x[b][c][t] directly (divergent float4 loads, line-reuse via L1/L2,
// x lives in L3). Serial-FMA step (~160 VALU + 24 trans / step). Weights
// left as raw uniform loads -> SGPRs, keeping VGPRs low so both prefetch
// buffers actually materialize.

#define TB 512
#define TT 4096
#define CHUNK 16
#define WARM 48
#define NCH (TT / CHUNK)  // 256
#define L2E 1.4426950408889634f

__device__ __forceinline__ float fexp2(float x) { return __builtin_amdgcn_exp2f(x); }
__device__ __forceinline__ float frcp(float x)  { return __builtin_amdgcn_rcpf(x); }

__global__ __launch_bounds__(64, 1) void gru_scan(
    const float* __restrict__ x, const float* __restrict__ wih,
    const float* __restrict__ whh, const float* __restrict__ bih,
    const float* __restrict__ bhh, float* __restrict__ out) {
  const int b  = blockIdx.x * 64 + threadIdx.x;
  const int ch = blockIdx.y;
  const int t0 = ch * CHUNK;
  const int tw = (t0 >= WARM) ? (t0 - WARM) : 0;
  const int gw = (t0 - tw) >> 2;  // warm 4-step groups: 0, 4, 8, or 12

  // Raw uniform weights (s_load -> SGPR; v_fma takes 1 SGPR operand).
  float Wi[12][4], Wh[12][4], bg[8], bnx[4], bnh[4];
#pragma unroll
  for (int g = 0; g < 12; ++g)
#pragma unroll
    for (int c = 0; c < 4; ++c) {
      Wi[g][c] = wih[g * 4 + c];
      Wh[g][c] = whh[g * 4 + c];
    }
#pragma unroll
  for (int g = 0; g < 8; ++g) bg[g] = bih[g] + bhh[g];
#pragma unroll
  for (int j = 0; j < 4; ++j) { bnx[j] = bih[8 + j]; bnh[j] = bhh[8 + j]; }

  float h0 = 0.f, h1 = 0.f, h2 = 0.f, h3 = 0.f;

  const float* bp0 = x + ((size_t)b * 4 + 0) * TT + tw;
  const float* bp1 = x + ((size_t)b * 4 + 1) * TT + tw;
  const float* bp2 = x + ((size_t)b * 4 + 2) * TT + tw;
  const float* bp3 = x + ((size_t)b * 4 + 3) * TT + tw;
  float* op0 = out + ((size_t)b * 4 + 0) * TT + t0;
  float* op1 = out + ((size_t)b * 4 + 1) * TT + t0;
  float* op2 = out + ((size_t)b * 4 + 2) * TT + t0;
  float* op3 = out + ((size_t)b * 4 + 3) * TT + t0;

#define STEP(xx0, xx1, xx2, xx3) do {                                        \
    float ar[8];                                                             \
    _Pragma("unroll") for (int g = 0; g < 8; ++g) {                          \
      float s = fmaf(Wi[g][0], (xx0), bg[g]);                                \
      s = fmaf(Wi[g][1], (xx1), s);                                          \
      s = fmaf(Wi[g][2], (xx2), s);                                          \
      s = fmaf(Wi[g][3], (xx3), s);                                          \
      s = fmaf(Wh[g][0], h0, s);                                             \
      s = fmaf(Wh[g][1], h1, s);                                             \
      s = fmaf(Wh[g][2], h2, s);                                             \
      ar[g] = fmaf(Wh[g][3], h3, s);                                         \
    }                                                                        \
    float rr[4], zz[4], nn[4];                                               \
    _Pragma("unroll") for (int j = 0; j < 4; ++j)                            \
      rr[j] = frcp(1.0f + fexp2(ar[j] * -L2E));                              \
    _Pragma("unroll") for (int j = 0; j < 4; ++j)                            \
      zz[j] = frcp(1.0f + fexp2(ar[4 + j] * -L2E));                          \
    _Pragma("unroll") for (int j = 0; j < 4; ++j) {                          \
      float u = fmaf(Wi[8 + j][0], (xx0), bnx[j]);                           \
      u = fmaf(Wi[8 + j][1], (xx1), u);                                      \
      u = fmaf(Wi[8 + j][2], (xx2), u);                                      \
      u = fmaf(Wi[8 + j][3], (xx3), u);                                      \
      float v = fmaf(Wh[8 + j][0], h0, bnh[j]);                              \
      v = fmaf(Wh[8 + j][1], h1, v);                                         \
      v = fmaf(Wh[8 + j][2], h2, v);                                         \
      v = fmaf(Wh[8 + j][3], h3, v);                                         \
      float arg = fmaf(rr[j], v, u) * (2.0f * L2E);                          \
      nn[j] = fmaf(-2.0f, frcp(1.0f + fexp2(arg)), 1.0f);                    \
    }                                                                        \
    h0 = fmaf(zz[0], h0 - nn[0], nn[0]);                                     \
    h1 = fmaf(zz[1], h1 - nn[1], nn[1]);                                     \
    h2 = fmaf(zz[2], h2 - nn[2], nn[2]);                                     \
    h3 = fmaf(zz[3], h3 - nn[3], nn[3]);                                     \
  } while (0)

  float4 A0, A1, A2, A3, B0, B1, B2, B3;
#define LDA(off) do { const int _o = (off);                                  \
    A0 = *(const float4*)(bp0 + _o); A1 = *(const float4*)(bp1 + _o);        \
    A2 = *(const float4*)(bp2 + _o); A3 = *(const float4*)(bp3 + _o); } while (0)
#define LDB(off) do { const int _o = (off);                                  \
    B0 = *(const float4*)(bp0 + _o); B1 = *(const float4*)(bp1 + _o);        \
    B2 = *(const float4*)(bp2 + _o); B3 = *(const float4*)(bp3 + _o); } while (0)
#define QUADA do { STEP(A0.x, A1.x, A2.x, A3.x); STEP(A0.y, A1.y, A2.y, A3.y); \
    STEP(A0.z, A1.z, A2.z, A3.z); STEP(A0.w, A1.w, A2.w, A3.w); } while (0)
#define QUADB do { STEP(B0.x, B1.x, B2.x, B3.x); STEP(B0.y, B1.y, B2.y, B3.y); \
    STEP(B0.z, B1.z, B2.z, B3.z); STEP(B0.w, B1.w, B2.w, B3.w); } while (0)
#define EQA(off) do { float4 o0, o1, o2, o3;                                 \
    STEP(A0.x, A1.x, A2.x, A3.x); o0.x = h0; o1.x = h1; o2.x = h2; o3.x = h3;\
    STEP(A0.y, A1.y, A2.y, A3.y); o0.y = h0; o1.y = h1; o2.y = h2; o3.y = h3;\
    STEP(A0.z, A1.z, A2.z, A3.z); o0.z = h0; o1.z = h1; o2.z = h2; o3.z = h3;\
    STEP(A0.w, A1.w, A2.w, A3.w); o0.w = h0; o1.w = h1; o2.w = h2; o3.w = h3;\
    *(float4*)(op0 + (off)) = o0; *(float4*)(op1 + (off)) = o1;              \
    *(float4*)(op2 + (off)) = o2; *(float4*)(op3 + (off)) = o3; } while (0)
#define EQB(off) do { float4 o0, o1, o2, o3;                                 \
    STEP(B0.x, B1.x, B2.x, B3.x); o0.x = h0; o1.x = h1; o2.x = h2; o3.x = h3;\
    STEP(B0.y, B1.y, B2.y, B3.y); o0.y = h0; o1.y = h1; o2.y = h2; o3.y = h3;\
    STEP(B0.z, B1.z, B2.z, B3.z); o0.z = h0; o1.z = h1; o2.z = h2; o3.z = h3;\
    STEP(B0.w, B1.w, B2.w, B3.w); o0.w = h0; o1.w = h1; o2.w = h2; o3.w = h3;\
    *(float4*)(op0 + (off)) = o0; *(float4*)(op1 + (off)) = o1;              \
    *(float4*)(op2 + (off)) = o2; *(float4*)(op3 + (off)) = o3; } while (0)

  // Warm phase: double-buffered 4-step groups, gw is even (0/4/8/12).
  LDA(0);
  for (int g = 0; g + 2 <= gw; g += 2) {
    LDB((g + 1) * 4);
    QUADA;
    LDA((g + 2) * 4);
    QUADB;
  }
  // Emit phase: 4 groups (A holds group gw), compile-time store offsets.
  const int e0 = gw * 4;
  LDB(e0 + 4);
  EQA(0);
  LDA(e0 + 8);
  EQB(4);
  LDB(e0 + 12);
  EQA(8);
  EQB(12);

#undef STEP
#undef LDA
#undef LDB
#undef QUADA
#undef QUADB
#undef EQA
#undef EQB
}

extern "C" void kernel_launch(void* const* d_in, const int* in_sizes, int n_in,
                              void* d_out, int out_size, void* d_ws, size_t ws_size,
                              hipStream_t stream) {
  const float* x   = (const float*)d_in[0];
  const float* wih = (const float*)d_in[1];
  const float* whh = (const float*)d_in[2];
  const float* bih = (const float*)d_in[3];
  const float* bhh = (const float*)d_in[4];
  float* out = (float*)d_out;

  gru_scan<<<dim3(TB / 64, NCH), 64, 0, stream>>>(x, wih, whh, bih, bhh, out);
}